// Round 1
// baseline (573.659 us; speedup 1.0000x reference)
//
#include <hip/hip_runtime.h>

typedef float f32x4 __attribute__((ext_vector_type(4)));

#define K 8                    // nodes per thread in kernel 1
#define NODES_PER_BLOCK 64     // 8 node-sets * K

// Kernel 1: y[node][j] for j in [0,128):
//   j <  64 : sum_h x[node][h] * W[j][h]        + b[j]   (bias folded into first half)
//   j >= 64 : sum_h x[node][h] * W[j-64][64+h]
// Vt[h][j] in LDS is the fused/transposed weight matrix (32 KB).
__global__ __launch_bounds__(256) void egcn_node_linear(
    const float* __restrict__ x, const float* __restrict__ W,
    const float* __restrict__ b, float* __restrict__ y, int n_nodes) {
  __shared__ float Vt[64][128];
  for (int i = threadIdx.x; i < 64 * 128; i += 256) {
    int o = i >> 7;        // W row (0..63)
    int h = i & 127;       // W col (0..127)
    float w = W[i];
    int j = (h < 64) ? o : (o + 64);
    Vt[h & 63][j] = w;
  }
  __syncthreads();

  const int jgrp = threadIdx.x & 31;   // 32 lanes cover 128 outputs (4 each)
  const int nset = threadIdx.x >> 5;   // 8 node-sets per block
  const int j0 = jgrp * 4;
  const int base = blockIdx.x * NODES_PER_BLOCK + nset * K;

  f32x4 acc[K];
#pragma unroll
  for (int k = 0; k < K; ++k) acc[k] = (f32x4){0.f, 0.f, 0.f, 0.f};

#pragma unroll 4
  for (int h4 = 0; h4 < 64; h4 += 4) {
    // 4 weight rows, 16B each, lanes read consecutive float4s -> conflict-free
    f32x4 w0 = *reinterpret_cast<const f32x4*>(&Vt[h4 + 0][j0]);
    f32x4 w1 = *reinterpret_cast<const f32x4*>(&Vt[h4 + 1][j0]);
    f32x4 w2 = *reinterpret_cast<const f32x4*>(&Vt[h4 + 2][j0]);
    f32x4 w3 = *reinterpret_cast<const f32x4*>(&Vt[h4 + 3][j0]);
#pragma unroll
    for (int k = 0; k < K; ++k) {
      int node = base + k;
      int nc = node < n_nodes ? node : (n_nodes - 1);  // clamp loads, guard stores
      f32x4 xv = *reinterpret_cast<const f32x4*>(&x[(long)nc * 64 + h4]);
      acc[k].x += xv.x * w0.x + xv.y * w1.x + xv.z * w2.x + xv.w * w3.x;
      acc[k].y += xv.x * w0.y + xv.y * w1.y + xv.z * w2.y + xv.w * w3.y;
      acc[k].z += xv.x * w0.z + xv.y * w1.z + xv.z * w2.z + xv.w * w3.z;
      acc[k].w += xv.x * w0.w + xv.y * w1.w + xv.z * w2.w + xv.w * w3.w;
    }
  }

  f32x4 bias = (f32x4){0.f, 0.f, 0.f, 0.f};
  if (j0 < 64) bias = *reinterpret_cast<const f32x4*>(&b[j0]);  // fold b into y1 half
#pragma unroll
  for (int k = 0; k < K; ++k) {
    int node = base + k;
    if (node < n_nodes) {
      f32x4 r = acc[k] + bias;
      *reinterpret_cast<f32x4*>(&y[(long)node * 128 + j0]) = r;
    }
  }
}

// Kernel 2: out[e][:] = y[src[e]][0:64] + y[dst[e]][64:128]
// 16 threads per edge, one float4 each; out store is nontemporal so the
// 410 MB output stream doesn't evict the 51 MB y buffer from L2.
__global__ __launch_bounds__(256) void egcn_edge_gather(
    const float* __restrict__ y, const int* __restrict__ ei,
    float* __restrict__ out, int n_edges) {
  long t = (long)blockIdx.x * 256 + threadIdx.x;
  int e = (int)(t >> 4);
  int lane = (int)(t & 15);
  if (e >= n_edges) return;
  int src = ei[e];
  int dst = ei[n_edges + e];
  f32x4 a = *reinterpret_cast<const f32x4*>(&y[(long)src * 128 + lane * 4]);
  f32x4 c = *reinterpret_cast<const f32x4*>(&y[(long)dst * 128 + 64 + lane * 4]);
  f32x4 r = a + c;
  __builtin_nontemporal_store(r, reinterpret_cast<f32x4*>(&out[(long)e * 64 + lane * 4]));
}

// Fallback (only if ws_size < 51.2 MB): fused per-edge linear, W in LDS.
__global__ __launch_bounds__(256) void egcn_fused_fallback(
    const float* __restrict__ x, const int* __restrict__ ei,
    const float* __restrict__ W, const float* __restrict__ b,
    float* __restrict__ out, int n_edges) {
  __shared__ float Vt[64][128];
  for (int i = threadIdx.x; i < 64 * 128; i += 256) {
    int o = i >> 7, h = i & 127;
    float w = W[i];
    int j = (h < 64) ? o : (o + 64);
    Vt[h & 63][j] = w;
  }
  __syncthreads();
  int e = blockIdx.x * 16 + (threadIdx.x >> 4);
  int o0 = (threadIdx.x & 15) * 4;
  if (e >= n_edges) return;
  int src = ei[e];
  int dst = ei[n_edges + e];
  f32x4 acc = *reinterpret_cast<const f32x4*>(&b[o0]);
#pragma unroll 4
  for (int h = 0; h < 64; ++h) {
    float xs = x[(long)src * 64 + h];
    float xd = x[(long)dst * 64 + h];
    acc += xs * *reinterpret_cast<const f32x4*>(&Vt[h][o0]);
    acc += xd * *reinterpret_cast<const f32x4*>(&Vt[h][o0 + 64]);
  }
  *reinterpret_cast<f32x4*>(&out[(long)e * 64 + o0]) = acc;
}

extern "C" void kernel_launch(void* const* d_in, const int* in_sizes, int n_in,
                              void* d_out, int out_size, void* d_ws, size_t ws_size,
                              hipStream_t stream) {
  const float* x  = (const float*)d_in[0];
  const int*   ei = (const int*)d_in[1];
  const float* W  = (const float*)d_in[2];
  const float* b  = (const float*)d_in[3];
  float* out = (float*)d_out;

  const int n_nodes = in_sizes[0] / 64;   // 100000
  const int n_edges = in_sizes[1] / 2;    // 1600000

  const size_t need = (size_t)n_nodes * 128 * sizeof(float);  // 51.2 MB
  if (ws_size >= need) {
    float* y = (float*)d_ws;
    int blocks1 = (n_nodes + NODES_PER_BLOCK - 1) / NODES_PER_BLOCK;
    egcn_node_linear<<<blocks1, 256, 0, stream>>>(x, W, b, y, n_nodes);
    long total = (long)n_edges * 16;
    int blocks2 = (int)((total + 255) / 256);
    egcn_edge_gather<<<blocks2, 256, 0, stream>>>(y, ei, out, n_edges);
  } else {
    int blocks = (n_edges + 15) / 16;
    egcn_fused_fallback<<<blocks, 256, 0, stream>>>(x, ei, W, b, out, n_edges);
  }
}

// Round 2
// 538.863 us; speedup vs baseline: 1.0646x; 1.0646x over previous
//
#include <hip/hip_runtime.h>

typedef float f32x4 __attribute__((ext_vector_type(4)));
typedef unsigned short u16x4 __attribute__((ext_vector_type(4)));

#define K 8                    // nodes per thread in kernel 1
#define NODES_PER_BLOCK 64     // 8 node-sets * K

// fp32 -> bf16 round-to-nearest-even (data is well-behaved, no NaN handling)
static __device__ inline unsigned short f2bf(float f) {
  unsigned int u = __float_as_uint(f);
  u += 0x7FFFu + ((u >> 16) & 1u);
  return (unsigned short)(u >> 16);
}
static __device__ inline float bf2f(unsigned short u) {
  return __uint_as_float(((unsigned int)u) << 16);
}

// Kernel 1: y[node][j] (bf16) for j in [0,128):
//   j <  64 : sum_h x[node][h] * W[j][h]      + b[j]  (bias folded here)
//   j >= 64 : sum_h x[node][h] * W[j-64][64+h]
// Vt[h][j] in LDS is the fused/transposed weight matrix (32 KB).
__global__ __launch_bounds__(256) void egcn_node_linear(
    const float* __restrict__ x, const float* __restrict__ W,
    const float* __restrict__ b, unsigned short* __restrict__ y, int n_nodes) {
  __shared__ float Vt[64][128];
  for (int i = threadIdx.x; i < 64 * 128; i += 256) {
    int o = i >> 7;        // W row (0..63)
    int h = i & 127;       // W col (0..127)
    float w = W[i];
    int j = (h < 64) ? o : (o + 64);
    Vt[h & 63][j] = w;
  }
  __syncthreads();

  const int jgrp = threadIdx.x & 31;   // 32 lanes cover 128 outputs (4 each)
  const int nset = threadIdx.x >> 5;   // 8 node-sets per block
  const int j0 = jgrp * 4;
  const int base = blockIdx.x * NODES_PER_BLOCK + nset * K;

  f32x4 acc[K];
#pragma unroll
  for (int k = 0; k < K; ++k) acc[k] = (f32x4){0.f, 0.f, 0.f, 0.f};

#pragma unroll 4
  for (int h4 = 0; h4 < 64; h4 += 4) {
    f32x4 w0 = *reinterpret_cast<const f32x4*>(&Vt[h4 + 0][j0]);
    f32x4 w1 = *reinterpret_cast<const f32x4*>(&Vt[h4 + 1][j0]);
    f32x4 w2 = *reinterpret_cast<const f32x4*>(&Vt[h4 + 2][j0]);
    f32x4 w3 = *reinterpret_cast<const f32x4*>(&Vt[h4 + 3][j0]);
#pragma unroll
    for (int k = 0; k < K; ++k) {
      int node = base + k;
      int nc = node < n_nodes ? node : (n_nodes - 1);  // clamp loads, guard stores
      f32x4 xv = *reinterpret_cast<const f32x4*>(&x[(long)nc * 64 + h4]);
      acc[k].x += xv.x * w0.x + xv.y * w1.x + xv.z * w2.x + xv.w * w3.x;
      acc[k].y += xv.x * w0.y + xv.y * w1.y + xv.z * w2.y + xv.w * w3.y;
      acc[k].z += xv.x * w0.z + xv.y * w1.z + xv.z * w2.z + xv.w * w3.z;
      acc[k].w += xv.x * w0.w + xv.y * w1.w + xv.z * w2.w + xv.w * w3.w;
    }
  }

  f32x4 bias = (f32x4){0.f, 0.f, 0.f, 0.f};
  if (j0 < 64) bias = *reinterpret_cast<const f32x4*>(&b[j0]);  // fold b
#pragma unroll
  for (int k = 0; k < K; ++k) {
    int node = base + k;
    if (node < n_nodes) {
      f32x4 r = acc[k] + bias;
      u16x4 pk;
      pk[0] = f2bf(r.x); pk[1] = f2bf(r.y); pk[2] = f2bf(r.z); pk[3] = f2bf(r.w);
      *reinterpret_cast<u16x4*>(&y[(unsigned)node * 128u + (unsigned)j0]) = pk;  // 8B store
    }
  }
}

// Kernel 2: out[e][:] = bf16_to_f32(y[src[e]][0:64]) + bf16_to_f32(y[dst[e]][64:128])
// 16 lanes/edge, each lane: 2x 8B bf16 gathers + 1x 16B fp32 NT store.
// NT store keeps the 410 MB output stream from evicting y (25.6 MB) from L2/L3.
__global__ __launch_bounds__(256) void egcn_edge_gather(
    const unsigned short* __restrict__ y, const int* __restrict__ ei,
    float* __restrict__ out, int n_edges) {
  unsigned int t = blockIdx.x * 256u + threadIdx.x;
  unsigned int e = t >> 4;
  unsigned int l = t & 15u;
  if (e >= (unsigned int)n_edges) return;
  unsigned int src = (unsigned int)ei[e];
  unsigned int dst = (unsigned int)ei[(unsigned int)n_edges + e];
  u16x4 a = *reinterpret_cast<const u16x4*>(y + src * 128u + l * 4u);
  u16x4 c = *reinterpret_cast<const u16x4*>(y + dst * 128u + 64u + l * 4u);
  f32x4 r;
  r.x = bf2f(a[0]) + bf2f(c[0]);
  r.y = bf2f(a[1]) + bf2f(c[1]);
  r.z = bf2f(a[2]) + bf2f(c[2]);
  r.w = bf2f(a[3]) + bf2f(c[3]);
  __builtin_nontemporal_store(r, reinterpret_cast<f32x4*>(out + e * 64u + l * 4u));
}

// Fallback (only if ws_size < 25.6 MB): fused per-edge linear, W in LDS.
__global__ __launch_bounds__(256) void egcn_fused_fallback(
    const float* __restrict__ x, const int* __restrict__ ei,
    const float* __restrict__ W, const float* __restrict__ b,
    float* __restrict__ out, int n_edges) {
  __shared__ float Vt[64][128];
  for (int i = threadIdx.x; i < 64 * 128; i += 256) {
    int o = i >> 7, h = i & 127;
    float w = W[i];
    int j = (h < 64) ? o : (o + 64);
    Vt[h & 63][j] = w;
  }
  __syncthreads();
  int e = blockIdx.x * 16 + (threadIdx.x >> 4);
  int o0 = (threadIdx.x & 15) * 4;
  if (e >= n_edges) return;
  int src = ei[e];
  int dst = ei[n_edges + e];
  f32x4 acc = *reinterpret_cast<const f32x4*>(&b[o0]);
#pragma unroll 4
  for (int h = 0; h < 64; ++h) {
    float xs = x[(long)src * 64 + h];
    float xd = x[(long)dst * 64 + h];
    acc += xs * *reinterpret_cast<const f32x4*>(&Vt[h][o0]);
    acc += xd * *reinterpret_cast<const f32x4*>(&Vt[h][o0 + 64]);
  }
  *reinterpret_cast<f32x4*>(&out[(long)e * 64 + o0]) = acc;
}

extern "C" void kernel_launch(void* const* d_in, const int* in_sizes, int n_in,
                              void* d_out, int out_size, void* d_ws, size_t ws_size,
                              hipStream_t stream) {
  const float* x  = (const float*)d_in[0];
  const int*   ei = (const int*)d_in[1];
  const float* W  = (const float*)d_in[2];
  const float* b  = (const float*)d_in[3];
  float* out = (float*)d_out;

  const int n_nodes = in_sizes[0] / 64;   // 100000
  const int n_edges = in_sizes[1] / 2;    // 1600000

  const size_t need = (size_t)n_nodes * 128 * sizeof(unsigned short);  // 25.6 MB
  if (ws_size >= need) {
    unsigned short* y = (unsigned short*)d_ws;
    int blocks1 = (n_nodes + NODES_PER_BLOCK - 1) / NODES_PER_BLOCK;
    egcn_node_linear<<<blocks1, 256, 0, stream>>>(x, W, b, y, n_nodes);
    long total = (long)n_edges * 16;
    int blocks2 = (int)((total + 255) / 256);
    egcn_edge_gather<<<blocks2, 256, 0, stream>>>(y, ei, out, n_edges);
  } else {
    int blocks = (n_edges + 15) / 16;
    egcn_fused_fallback<<<blocks, 256, 0, stream>>>(x, ei, W, b, out, n_edges);
  }
}